// Round 6
// baseline (495.415 us; speedup 1.0000x reference)
//
#include <hip/hip_runtime.h>
#include <hip/hip_bf16.h>

#define B_GRAPHS 16384
#define NN (B_GRAPHS * 5)          // 81920 nodes
#define NE (NN * 4)                // 327680 edges
#define GPB 4                      // graphs per block
#define EPB 80                     // edges per block
#define NPB 20                     // nodes per block

typedef __attribute__((ext_vector_type(8))) short bf8;   // 8 x bf16
typedef __attribute__((ext_vector_type(4))) short s4;    // 4 x bf16
typedef __attribute__((ext_vector_type(4))) float f4;
typedef __attribute__((ext_vector_type(2))) unsigned u2;
typedef __attribute__((ext_vector_type(4))) unsigned u4;

// d_ws layout (bf16 elements) — all weights transposed to [N=96][K]
#define OFF_EW1 0
#define OFF_EW2 27648
#define OFF_KW  36864
#define OFF_VW  55296
#define OFF_QW  64512
#define OFF_NW1 73728
#define OFF_NW2 92160
#define OFF_XW1 101376
#define OFF_XW2 129024
#define OFF_CW1 138240
#define OFF_CW2 147456

__device__ __forceinline__ float sp_f(float x) {
    return fmaxf(x, 0.0f) + __logf(1.0f + __expf(-fabsf(x)));
}
__device__ __forceinline__ short tobf(float x) {
    return __builtin_bit_cast(short, __float2bfloat16(x));
}
__device__ __forceinline__ float frombf(short s) {
    union { float f; unsigned u; } v;
    v.u = ((unsigned)(unsigned short)s) << 16;
    return v.f;
}
__device__ __forceinline__ unsigned pk2(float a, float b) {
    unsigned lo = (unsigned short)tobf(a);
    unsigned hi = (unsigned short)tobf(b);
    return lo | (hi << 16);
}
// swizzled bf16 LDS frag read: row-major [rows][96], elem ^ ((row&7)<<3)
__device__ __forceinline__ bf8 ldfrag(const short* buf, int row, int k) {
    return *(const bf8*)&buf[(row * 96 + k) ^ ((row & 7) << 3)];
}
// pack 4 f32 -> 4 bf16, store 8B at swizzled addr (col0 multiple of 4)
__device__ __forceinline__ void stpk(short* buf, int row, int col0, f4 v) {
    u2 o = {pk2(v[0], v[1]), pk2(v[2], v[3])};
    *(u2*)&buf[(row * 96 + col0) ^ ((row & 7) << 3)] = o;
}
// pack 8 f32 -> 8 bf16, store 16B at swizzled addr (col0 multiple of 8)
__device__ __forceinline__ void stpk8(short* buf, int row, int col0,
                                      const float* v) {
    u4 o = {pk2(v[0], v[1]), pk2(v[2], v[3]), pk2(v[4], v[5]), pk2(v[6], v[7])};
    *(u4*)&buf[(row * 96 + col0) ^ ((row & 7) << 3)] = o;
}
// f32 scratch swizzle (outb): elem ^ ((row&7)<<2), keeps f4 alignment
__device__ __forceinline__ float* oaddr(float* b, int row, int col) {
    return &b[(row * 96 + col) ^ ((row & 7) << 2)];
}
// direct-global ea fragment: 2 x f4 load + convert to bf8
__device__ __forceinline__ bf8 ld_ea8(const float* __restrict__ ea, int base,
                                      int k) {
    f4 a = *(const f4*)(ea + base + k);
    f4 b = *(const f4*)(ea + base + k + 4);
    bf8 r;
    r[0] = tobf(a[0]); r[1] = tobf(a[1]); r[2] = tobf(a[2]); r[3] = tobf(a[3]);
    r[4] = tobf(b[0]); r[5] = tobf(b[1]); r[6] = tobf(b[2]); r[7] = tobf(b[3]);
    return r;
}

// Wave-owns-16-cols GEMM, swapped MFMA operands.
// acc[s][j] = out[row = s*16 + (lane&15)][col = wc0 + (lane>>4)*4 + j]
template <int K, int NS, class AF>
__device__ __forceinline__ void gemmCol(const short* __restrict__ wT, int wc0,
                                        int ln, int kg, AF aload, f4* acc) {
#pragma unroll
    for (int s = 0; s < NS; s++) {
        acc[s][0] = 0.f; acc[s][1] = 0.f; acc[s][2] = 0.f; acc[s][3] = 0.f;
    }
    __builtin_amdgcn_s_setprio(1);
#pragma unroll
    for (int k0 = 0; k0 < K; k0 += 32) {
        bf8 wf = *(const bf8*)(wT + (size_t)(wc0 + ln) * K + k0 + kg * 8);
#pragma unroll
        for (int s = 0; s < NS; s++) {
            acc[s] = __builtin_amdgcn_mfma_f32_16x16x32_bf16(wf, aload(s, k0),
                                                             acc[s], 0, 0, 0);
        }
    }
    __builtin_amdgcn_s_setprio(0);
}

// ---------------- Prep: transpose+convert weights into d_ws ------------------
__global__ __launch_bounds__(256) void k_prep(
    const float* ew1, const float* ew2, const float* kw, const float* vw,
    const float* qw, const float* nw1, const float* nw2, const float* xw1,
    const float* xw2, const float* cw1, const float* cw2, short* wsT) {
    const float* srcs[11] = {ew1, ew2, kw, vw, qw, nw1, nw2, xw1, xw2, cw1, cw2};
    const int Ks[11] = {288, 96, 192, 96, 96, 192, 96, 288, 96, 96, 96};
    const int offs[11] = {OFF_EW1, OFF_EW2, OFF_KW, OFF_VW, OFF_QW, OFF_NW1,
                          OFF_NW2, OFF_XW1, OFF_XW2, OFF_CW1, OFF_CW2};
    int b = blockIdx.x;
    const float* src = srcs[b];
    int K = Ks[b], off = offs[b];
    for (int idx = threadIdx.x; idx < K * 96; idx += 256) {
        int n = idx / K, k = idx - n * K;
        wsT[off + idx] = tobf(src[(size_t)k * 96 + n]);
    }
}

// ---------------- Fused: edge MLP + attention + node + enhance + coord -------
__global__ __launch_bounds__(384, 4) void k_fused(
    const float* __restrict__ h, const float* __restrict__ cp,
    const float* __restrict__ ea, const short* __restrict__ wsT,
    const float* __restrict__ eb1, const float* __restrict__ eb2,
    const float* __restrict__ qb, const float* __restrict__ kb,
    const float* __restrict__ vb, const float* __restrict__ nb1,
    const float* __restrict__ nb2, const float* __restrict__ g1,
    const float* __restrict__ be1, const float* __restrict__ g2,
    const float* __restrict__ be2, const float* __restrict__ xb1,
    const float* __restrict__ xb2, const float* __restrict__ cb1,
    const float* __restrict__ cb2, const float* __restrict__ cw3,
    const float* __restrict__ cb3,
    float* __restrict__ accg, float* __restrict__ hng, float* __restrict__ efg) {
    // LDS: 24960 shorts (49,920 B) + 848 f32 (3,392 B) = 53,312 B -> 3 blk/CU
    __shared__ __align__(16) short smem[24960];
    __shared__ __align__(16) float fpool[848];
    short* hb  = smem;            // [20][96] h -> later hn
    short* S1  = smem + 1920;     // [80][96] scratch; rows 48-67 host qh/agb
    short* efb = smem + 9600;     // [80][96] ef -> ef2 (A0)
    short* kvb = smem + 17280;    // [80][96] kh -> vh -> A2 ; hosts outb f32
    short* qag = S1 + 48 * 96;    // [20][96] qh -> agb (inside S1)
    float* outb = (float*)kvb;    // [20][96] f32 (swizzled via oaddr)
    float* sc   = fpool;          // 240: scores/attw ; later bcb
    float* trs  = fpool + 240;    // 320
    float* cw3s = fpool + 560;    // 288

    const int t = threadIdx.x;
    const int blk = blockIdx.x;
    const int n0 = blk * NPB, e0 = blk * EPB;

    // ---- P0: stage h (bf16, swizzled) + cw3 ----
    for (int i = t; i < 480; i += 384) {
        int r = i / 24, c = (i - r * 24) * 4;
        f4 v = *(const f4*)&h[(size_t)(n0 + r) * 96 + c];
        f4 w = *(const f4*)&h[(size_t)(n0 + r) * 96 + c];
        (void)w;
        stpk(hb, r, c, v);
    }
    if (t < 288) cw3s[t] = cw3[t];
    __syncthreads();

    const int lane = t & 63, w = t >> 6;
    const int kg = lane >> 4, ln = lane & 15;
    const int wc0 = w * 16, col0 = wc0 + kg * 4;

    int erow[5], esrc[5], edst[5], eabase[5];
#pragma unroll
    for (int s = 0; s < 5; s++) {
        erow[s] = s * 16 + ln;
        int sl = erow[s] >> 2;
        esrc[s] = sl;
        int si = sl % 5, jj = erow[s] & 3;
        edst[s] = (sl / 5) * 5 + jj + (jj >= si);
        eabase[s] = (e0 + erow[s]) * 96;
    }

    f4 acc[5];
    // ---- P1: edge MLP L1 (K=288: [h[src], h[dst], ea(global)]) -> S1 ----
    gemmCol<288, 5>(wsT + OFF_EW1, wc0, ln, kg,
        [&](int s, int k0) -> bf8 {
            int k = k0 + kg * 8;
            if (k0 < 96)  return ldfrag(hb, esrc[s], k);
            if (k0 < 192) return ldfrag(hb, edst[s], k - 96);
            return ld_ea8(ea, eabase[s], k - 192);
        }, acc);
    {
        f4 b = *(const f4*)&eb1[col0];
#pragma unroll
        for (int s = 0; s < 5; s++) {
            f4 v;
#pragma unroll
            for (int j = 0; j < 4; j++) v[j] = sp_f(acc[s][j] + b[j]);
            stpk(S1, erow[s], col0, v);
        }
    }
    __syncthreads();
    // ---- P2: edge MLP L2 (K=96) -> efb (ef) ----
    gemmCol<96, 5>(wsT + OFF_EW2, wc0, ln, kg,
        [&](int s, int k0) { return ldfrag(S1, erow[s], k0 + kg * 8); }, acc);
    {
        f4 b = *(const f4*)&eb2[col0];
#pragma unroll
        for (int s = 0; s < 5; s++) {
            f4 v;
#pragma unroll
            for (int j = 0; j < 4; j++) v[j] = sp_f(acc[s][j] + b[j]);
            stpk(efb, erow[s], col0, v);
        }
    }
    __syncthreads();
    // ---- P3: q proj -> qag (S1 rows 48-67) ; P4: kh (K=192) -> kvb ----
    {
        f4 qa[2];
        gemmCol<96, 2>(wsT + OFF_QW, wc0, ln, kg,
            [&](int s, int k0) { return ldfrag(hb, s * 16 + ln, k0 + kg * 8); }, qa);
        f4 b = *(const f4*)&qb[col0];
#pragma unroll
        for (int s = 0; s < 2; s++) {
            int row = s * 16 + ln;
            if (row < NPB) {
                f4 v;
#pragma unroll
                for (int j = 0; j < 4; j++) v[j] = qa[s][j] + b[j];
                stpk(qag, row, col0, v);
            }
        }
    }
    gemmCol<192, 5>(wsT + OFF_KW, wc0, ln, kg,
        [&](int s, int k0) {
            int k = k0 + kg * 8;
            if (k0 < 96) return ldfrag(hb, esrc[s], k);
            return ldfrag(efb, erow[s], k - 96);
        }, acc);
    {
        f4 b = *(const f4*)&kb[col0];
#pragma unroll
        for (int s = 0; s < 5; s++) {
            f4 v;
#pragma unroll
            for (int j = 0; j < 4; j++) v[j] = acc[s][j] + b[j];
            stpk(kvb, erow[s], col0, v);
        }
    }
    __syncthreads();
    // ---- P5a: scores (per edge x head) ----
    if (t < 240) {
        int e = t / 3, hd = t - e * 3, nd = e >> 2;
        float s = 0.f;
#pragma unroll
        for (int c8 = 0; c8 < 4; c8++) {
            int c = hd * 32 + c8 * 8;
            bf8 qv = ldfrag(qag, nd, c);
            bf8 kv = ldfrag(kvb, e, c);
#pragma unroll
            for (int j = 0; j < 8; j++) s = fmaf(frombf(qv[j]), frombf(kv[j]), s);
        }
        sc[e * 3 + hd] = s * 0.17677669529663687f;  // 1/sqrt(32)
    }
    __syncthreads();
    // ---- P5b: softmax over 4 edges ; P6: vh (K=96) -> kvb ----
    if (t < 60) {
        int nd = t / 3, hd = t - nd * 3;
        float v0 = sc[(nd * 4 + 0) * 3 + hd], v1 = sc[(nd * 4 + 1) * 3 + hd];
        float v2 = sc[(nd * 4 + 2) * 3 + hd], v3 = sc[(nd * 4 + 3) * 3 + hd];
        float m = fmaxf(fmaxf(v0, v1), fmaxf(v2, v3));
        float p0 = __expf(v0 - m), p1 = __expf(v1 - m);
        float p2 = __expf(v2 - m), p3 = __expf(v3 - m);
        float inv = 1.f / (p0 + p1 + p2 + p3);
        sc[(nd * 4 + 0) * 3 + hd] = p0 * inv;
        sc[(nd * 4 + 1) * 3 + hd] = p1 * inv;
        sc[(nd * 4 + 2) * 3 + hd] = p2 * inv;
        sc[(nd * 4 + 3) * 3 + hd] = p3 * inv;
    }
    gemmCol<96, 5>(wsT + OFF_VW, wc0, ln, kg,
        [&](int s, int k0) { return ldfrag(efb, erow[s], k0 + kg * 8); }, acc);
    {
        f4 b = *(const f4*)&vb[col0];
#pragma unroll
        for (int s = 0; s < 5; s++) {
            f4 v;
#pragma unroll
            for (int j = 0; j < 4; j++) v[j] = acc[s][j] + b[j];
            stpk(kvb, erow[s], col0, v);   // P5a readers done at last barrier
        }
    }
    __syncthreads();
    // ---- P7: agg = sum attw*vh ; LayerNorm1 -> qag (vectorized) ----
    if (t < 320) {
        int nd = t >> 4, cg = t & 15;
        bool act = cg < 12;
        int hd = cg >> 2;
        float agg[8];
#pragma unroll
        for (int j = 0; j < 8; j++) agg[j] = 0.f;
        if (act) {
#pragma unroll
            for (int k = 0; k < 4; k++) {
                int e = nd * 4 + k;
                float wgt = sc[e * 3 + hd];
                bf8 v8 = ldfrag(kvb, e, cg * 8);
#pragma unroll
                for (int j = 0; j < 8; j++) agg[j] = fmaf(wgt, frombf(v8[j]), agg[j]);
            }
        }
        float s1 = 0.f, s2 = 0.f;
#pragma unroll
        for (int j = 0; j < 8; j++) { s1 += agg[j]; s2 += agg[j] * agg[j]; }
        if (!act) { s1 = 0.f; s2 = 0.f; }
        for (int m = 1; m < 16; m <<= 1) {
            s1 += __shfl_xor(s1, m);
            s2 += __shfl_xor(s2, m);
        }
        float mu = s1 * (1.f / 96.f);
        float var = s2 * (1.f / 96.f) - mu * mu;
        float rs = rsqrtf(var + 1e-5f);
        if (act) {
            int c = cg * 8;
            f4 ga = *(const f4*)&g1[c], gb = *(const f4*)&g1[c + 4];
            f4 ba = *(const f4*)&be1[c], bb = *(const f4*)&be1[c + 4];
            float o[8];
#pragma unroll
            for (int j = 0; j < 4; j++) {
                o[j] = (agg[j] - mu) * rs * ga[j] + ba[j];
                o[j + 4] = (agg[j + 4] - mu) * rs * gb[j] + bb[j];
            }
            stpk8(qag, nd, c, o);
        }
    }
    __syncthreads();
    // ---- P8: node MLP L1 (K=192: [h, agg]) -> S1 rows 0-31 ----
    {
        f4 na[2];
        gemmCol<192, 2>(wsT + OFF_NW1, wc0, ln, kg,
            [&](int s, int k0) {
                int row = s * 16 + ln, k = k0 + kg * 8;
                if (k0 < 96) return ldfrag(hb, row, k);
                return ldfrag(qag, row, k - 96);   // rows>=20 read garbage, ok
            }, na);
        f4 b = *(const f4*)&nb1[col0];
#pragma unroll
        for (int s = 0; s < 2; s++) {
            int row = s * 16 + ln;
            f4 v;
#pragma unroll
            for (int j = 0; j < 4; j++) v[j] = sp_f(na[s][j] + b[j]);
            stpk(S1, row, col0, v);   // garbage rows 20-31 harmless
        }
    }
    __syncthreads();
    // ---- P9: node MLP L2 (K=96) + residual h -> outb (swizzled f32) ----
    {
        f4 na[2];
        gemmCol<96, 2>(wsT + OFF_NW2, wc0, ln, kg,
            [&](int s, int k0) { return ldfrag(S1, s * 16 + ln, k0 + kg * 8); }, na);
        f4 b = *(const f4*)&nb2[col0];
#pragma unroll
        for (int s = 0; s < 2; s++) {
            int row = s * 16 + ln;
            if (row < NPB) {
                f4 hv = *(const f4*)&h[(size_t)(n0 + row) * 96 + col0];
                f4 v;
#pragma unroll
                for (int j = 0; j < 4; j++) v[j] = na[s][j] + b[j] + hv[j];
                *(f4*)oaddr(outb, row, col0) = v;
            }
        }
    }
    __syncthreads();
    // ---- P10: LayerNorm2 -> hng global + hb (vectorized) ----
    if (t < 320) {
        int nd = t >> 4, cg = t & 15;
        bool act = cg < 12;
        float xv[8];
#pragma unroll
        for (int j = 0; j < 8; j++) xv[j] = 0.f;
        if (act) {
            f4 x0 = *(const f4*)oaddr(outb, nd, cg * 8);
            f4 x1 = *(const f4*)oaddr(outb, nd, cg * 8 + 4);
#pragma unroll
            for (int j = 0; j < 4; j++) { xv[j] = x0[j]; xv[j + 4] = x1[j]; }
        }
        float s1 = 0.f, s2 = 0.f;
#pragma unroll
        for (int j = 0; j < 8; j++) { s1 += xv[j]; s2 += xv[j] * xv[j]; }
        for (int m = 1; m < 16; m <<= 1) {
            s1 += __shfl_xor(s1, m);
            s2 += __shfl_xor(s2, m);
        }
        float mu = s1 * (1.f / 96.f);
        float var = s2 * (1.f / 96.f) - mu * mu;
        float rs = rsqrtf(var + 1e-5f);
        if (act) {
            int c = cg * 8;
            f4 ga = *(const f4*)&g2[c], gb = *(const f4*)&g2[c + 4];
            f4 ba = *(const f4*)&be2[c], bb = *(const f4*)&be2[c + 4];
            float o[8];
#pragma unroll
            for (int j = 0; j < 4; j++) {
                o[j] = (xv[j] - mu) * rs * ga[j] + ba[j];
                o[j + 4] = (xv[j + 4] - mu) * rs * gb[j] + bb[j];
            }
            f4 o0 = {o[0], o[1], o[2], o[3]}, o1 = {o[4], o[5], o[6], o[7]};
            *(f4*)&hng[(size_t)(n0 + nd) * 96 + c] = o0;
            *(f4*)&hng[(size_t)(n0 + nd) * 96 + c + 4] = o1;
            stpk8(hb, nd, c, o);
        }
    }
    __syncthreads();
    // ---- P11: enhance L1 (K=288: [hn[src], hn[dst], ea(global)]) -> S1 ----
    gemmCol<288, 5>(wsT + OFF_XW1, wc0, ln, kg,
        [&](int s, int k0) -> bf8 {
            int k = k0 + kg * 8;
            if (k0 < 96)  return ldfrag(hb, esrc[s], k);
            if (k0 < 192) return ldfrag(hb, edst[s], k - 96);
            return ld_ea8(ea, eabase[s], k - 192);
        }, acc);
    {
        f4 b = *(const f4*)&xb1[col0];
#pragma unroll
        for (int s = 0; s < 5; s++) {
            f4 v;
#pragma unroll
            for (int j = 0; j < 4; j++) v[j] = sp_f(acc[s][j] + b[j]);
            stpk(S1, erow[s], col0, v);
        }
    }
    __syncthreads();
    // ---- P12: enhance L2 (K=96) + ef residual -> efg global + efb ----
    gemmCol<96, 5>(wsT + OFF_XW2, wc0, ln, kg,
        [&](int s, int k0) { return ldfrag(S1, erow[s], k0 + kg * 8); }, acc);
    {
        f4 b = *(const f4*)&xb2[col0];
#pragma unroll
        for (int s = 0; s < 5; s++) {
            int row = erow[s];
            s4 ev = *(const s4*)&efb[(row * 96 + col0) ^ ((row & 7) << 3)];
            f4 v;
#pragma unroll
            for (int j = 0; j < 4; j++) v[j] = acc[s][j] + b[j] + frombf(ev[j]);
            *(f4*)&efg[(size_t)(e0 + row) * 96 + col0] = v;
            stpk(efb, row, col0, v);
        }
    }
    __syncthreads();
    // ---- P13: coord MLP L1 (K=96) -> S1 ----
    gemmCol<96, 5>(wsT + OFF_CW1, wc0, ln, kg,
        [&](int s, int k0) { return ldfrag(efb, erow[s], k0 + kg * 8); }, acc);
    {
        f4 b = *(const f4*)&cb1[col0];
#pragma unroll
        for (int s = 0; s < 5; s++) {
            f4 v;
#pragma unroll
            for (int j = 0; j < 4; j++) v[j] = sp_f(acc[s][j] + b[j]);
            stpk(S1, erow[s], col0, v);
        }
    }
    __syncthreads();
    // ---- P14: coord MLP L2 (K=96) -> kvb (A2) ----
    gemmCol<96, 5>(wsT + OFF_CW2, wc0, ln, kg,
        [&](int s, int k0) { return ldfrag(S1, erow[s], k0 + kg * 8); }, acc);
    {
        f4 b = *(const f4*)&cb2[col0];
#pragma unroll
        for (int s = 0; s < 5; s++) {
            f4 v;
#pragma unroll
            for (int j = 0; j < 4; j++) v[j] = sp_f(acc[s][j] + b[j]);
            stpk(kvb, erow[s], col0, v);
        }
    }
    __syncthreads();
    // ---- P15: bc = A2 @ cw3 + cb3 -> sc region (bcb) ----
    if (t < 240) {
        int e = t / 3, j = t - e * 3;
        float s = cb3[j];
#pragma unroll
        for (int c8 = 0; c8 < 12; c8++) {
            bf8 av = ldfrag(kvb, e, c8 * 8);
#pragma unroll
            for (int jj = 0; jj < 8; jj++)
                s = fmaf(frombf(av[jj]), cw3s[(c8 * 8 + jj) * 3 + j], s);
        }
        sc[e * 3 + j] = s;
    }
    __syncthreads();
    // ---- P16: geometry per edge -> trs ----
    if (t < 80) {
        int sl = t >> 2, jj = t & 3, si = sl % 5;
        int dl = (sl / 5) * 5 + jj + (jj >= si);
        int rn = n0 + sl, cn = n0 + dl;
        float r0c = cp[(size_t)rn * 3 + 0], r1c = cp[(size_t)rn * 3 + 1],
              r2c = cp[(size_t)rn * 3 + 2];
        float q0 = cp[(size_t)cn * 3 + 0], q1 = cp[(size_t)cn * 3 + 1],
              q2 = cp[(size_t)cn * 3 + 2];
        float d0 = r0c - q0, d1 = r1c - q1, d2 = r2c - q2;
        float x0 = r1c * q2 - r2c * q1;
        float x1 = r2c * q0 - r0c * q2;
        float x2 = r0c * q1 - r1c * q0;
        float v0 = d1 * x2 - d2 * x1;
        float v1 = d2 * x0 - d0 * x2;
        float v2 = d0 * x1 - d1 * x0;
        float b0 = sc[t * 3 + 0], b1 = sc[t * 3 + 1], b2 = sc[t * 3 + 2];
        trs[t * 4 + 0] = fminf(fmaxf(d0 * b0 + x0 * b1 + v0 * b2, -100.f), 100.f);
        trs[t * 4 + 1] = fminf(fmaxf(d1 * b0 + x1 * b1 + v1 * b2, -100.f), 100.f);
        trs[t * 4 + 2] = fminf(fmaxf(d2 * b0 + x2 * b1 + v2 * b2, -100.f), 100.f);
    }
    __syncthreads();
    // ---- P17: acc = mean over each node's 4 edges ----
    if (t < 60) {
        int nd = t / 3, j = t - nd * 3;
        float s = (trs[(nd * 4 + 0) * 4 + j] + trs[(nd * 4 + 1) * 4 + j] +
                   trs[(nd * 4 + 2) * 4 + j] + trs[(nd * 4 + 3) * 4 + j]) * 0.25f;
        accg[(size_t)(n0 + nd) * 3 + j] = s;
    }
}

extern "C" void kernel_launch(void* const* d_in, const int* in_sizes, int n_in,
                              void* d_out, int out_size, void* d_ws, size_t ws_size,
                              hipStream_t stream) {
    const float* h   = (const float*)d_in[0];
    const float* cp  = (const float*)d_in[3];   // coord_pre
    const float* ea  = (const float*)d_in[5];   // edge_attr
    const float* ew1 = (const float*)d_in[6];
    const float* eb1 = (const float*)d_in[7];
    const float* ew2 = (const float*)d_in[8];
    const float* eb2 = (const float*)d_in[9];
    const float* xw1 = (const float*)d_in[10];
    const float* xb1 = (const float*)d_in[11];
    const float* xw2 = (const float*)d_in[12];
    const float* xb2 = (const float*)d_in[13];
    const float* nw1 = (const float*)d_in[14];
    const float* nb1 = (const float*)d_in[15];
    const float* nw2 = (const float*)d_in[16];
    const float* nb2 = (const float*)d_in[17];
    const float* cw1 = (const float*)d_in[18];
    const float* cb1 = (const float*)d_in[19];
    const float* cw2 = (const float*)d_in[20];
    const float* cb2 = (const float*)d_in[21];
    const float* cw3 = (const float*)d_in[22];
    const float* cb3 = (const float*)d_in[23];
    const float* qw  = (const float*)d_in[24];
    const float* qb  = (const float*)d_in[25];
    const float* kw  = (const float*)d_in[26];
    const float* kb  = (const float*)d_in[27];
    const float* vw  = (const float*)d_in[28];
    const float* vb  = (const float*)d_in[29];
    const float* g1  = (const float*)d_in[30];
    const float* be1 = (const float*)d_in[31];
    const float* g2  = (const float*)d_in[32];
    const float* be2 = (const float*)d_in[33];

    float* out  = (float*)d_out;
    float* accg = out;                                    // [NN,3]
    float* hng  = out + (size_t)NN * 3;                   // [NN,96]
    float* efg  = out + (size_t)NN * 3 + (size_t)NN * 96; // [NE,96] ef2
    short* wsT = (short*)d_ws;                            // 313 KB of weights

    k_prep<<<11, 256, 0, stream>>>(ew1, ew2, kw, vw, qw, nw1, nw2, xw1, xw2,
                                   cw1, cw2, wsT);
    k_fused<<<B_GRAPHS / GPB, 384, 0, stream>>>(
        h, cp, ea, wsT, eb1, eb2, qb, kb, vb, nb1, nb2, g1, be1, g2, be2,
        xb1, xb2, cb1, cb2, cw3, cb3, accg, hng, efg);
}

// Round 7
// 355.842 us; speedup vs baseline: 1.3922x; 1.3922x over previous
//
#include <hip/hip_runtime.h>
#include <hip/hip_bf16.h>

#define B_GRAPHS 16384
#define NN (B_GRAPHS * 5)          // 81920 nodes
#define NE (NN * 4)                // 327680 edges
#define GPB 4                      // graphs per block
#define EPB 80                     // edges per block
#define NPB 20                     // nodes per block

typedef __attribute__((ext_vector_type(8))) short bf8;   // 8 x bf16
typedef __attribute__((ext_vector_type(4))) short s4;    // 4 x bf16
typedef __attribute__((ext_vector_type(4))) float f4;
typedef __attribute__((ext_vector_type(2))) unsigned u2;
typedef __attribute__((ext_vector_type(4))) unsigned u4;

// d_ws layout (bf16 elements) — all weights transposed to [N=96][K]
#define OFF_EW1 0
#define OFF_EW2 27648
#define OFF_KW  36864
#define OFF_VW  55296
#define OFF_QW  64512
#define OFF_NW1 73728
#define OFF_NW2 92160
#define OFF_XW1 101376
#define OFF_XW2 129024
#define OFF_CW1 138240
#define OFF_CW2 147456

__device__ __forceinline__ float sp_f(float x) {
    return fmaxf(x, 0.0f) + __logf(1.0f + __expf(-fabsf(x)));
}
__device__ __forceinline__ short tobf(float x) {
    return __builtin_bit_cast(short, __float2bfloat16(x));
}
__device__ __forceinline__ float frombf(short s) {
    union { float f; unsigned u; } v;
    v.u = ((unsigned)(unsigned short)s) << 16;
    return v.f;
}
__device__ __forceinline__ unsigned pk2(float a, float b) {
    unsigned lo = (unsigned short)tobf(a);
    unsigned hi = (unsigned short)tobf(b);
    return lo | (hi << 16);
}
// swizzled bf16 LDS frag read: row-major [rows][96], elem ^ ((row&7)<<3)
__device__ __forceinline__ bf8 ldfrag(const short* buf, int row, int k) {
    return *(const bf8*)&buf[(row * 96 + k) ^ ((row & 7) << 3)];
}
// pack 4 f32 -> 4 bf16, store 8B at swizzled addr (col0 multiple of 4)
__device__ __forceinline__ void stpk(short* buf, int row, int col0, f4 v) {
    u2 o = {pk2(v[0], v[1]), pk2(v[2], v[3])};
    *(u2*)&buf[(row * 96 + col0) ^ ((row & 7) << 3)] = o;
}
// pack 8 f32 -> 8 bf16, store 16B at swizzled addr (col0 multiple of 8)
__device__ __forceinline__ void stpk8(short* buf, int row, int col0,
                                      const float* v) {
    u4 o = {pk2(v[0], v[1]), pk2(v[2], v[3]), pk2(v[4], v[5]), pk2(v[6], v[7])};
    *(u4*)&buf[(row * 96 + col0) ^ ((row & 7) << 3)] = o;
}
// f32 scratch swizzle (outb): elem ^ ((row&7)<<2), keeps f4 alignment
__device__ __forceinline__ float* oaddr(float* b, int row, int col) {
    return &b[(row * 96 + col) ^ ((row & 7) << 2)];
}

// Wave-owns-16-cols GEMM, swapped MFMA operands.
// acc[s][j] = out[row = s*16 + (lane&15)][col = wc0 + (lane>>4)*4 + j]
template <int K, int NS, class AF>
__device__ __forceinline__ void gemmCol(const short* __restrict__ wT, int wc0,
                                        int ln, int kg, AF aload, f4* acc) {
#pragma unroll
    for (int s = 0; s < NS; s++) {
        acc[s][0] = 0.f; acc[s][1] = 0.f; acc[s][2] = 0.f; acc[s][3] = 0.f;
    }
#pragma unroll
    for (int k0 = 0; k0 < K; k0 += 32) {
        bf8 wf = *(const bf8*)(wT + (size_t)(wc0 + ln) * K + k0 + kg * 8);
#pragma unroll
        for (int s = 0; s < NS; s++) {
            acc[s] = __builtin_amdgcn_mfma_f32_16x16x32_bf16(wf, aload(s, k0),
                                                             acc[s], 0, 0, 0);
        }
    }
}

// ---------------- Prep: transpose+convert weights into d_ws ------------------
__global__ __launch_bounds__(256) void k_prep(
    const float* ew1, const float* ew2, const float* kw, const float* vw,
    const float* qw, const float* nw1, const float* nw2, const float* xw1,
    const float* xw2, const float* cw1, const float* cw2, short* wsT) {
    const float* srcs[11] = {ew1, ew2, kw, vw, qw, nw1, nw2, xw1, xw2, cw1, cw2};
    const int Ks[11] = {288, 96, 192, 96, 96, 192, 96, 288, 96, 96, 96};
    const int offs[11] = {OFF_EW1, OFF_EW2, OFF_KW, OFF_VW, OFF_QW, OFF_NW1,
                          OFF_NW2, OFF_XW1, OFF_XW2, OFF_CW1, OFF_CW2};
    int b = blockIdx.x;
    const float* src = srcs[b];
    int K = Ks[b], off = offs[b];
    for (int idx = threadIdx.x; idx < K * 96; idx += 256) {
        int n = idx / K, k = idx - n * K;
        wsT[off + idx] = tobf(src[(size_t)k * 96 + n]);
    }
}

// ---------------- Fused: edge MLP + attention + node + enhance + coord -------
__global__ __launch_bounds__(384, 4) void k_fused(
    const float* __restrict__ h, const float* __restrict__ cp,
    const float* __restrict__ ea, const short* __restrict__ wsT,
    const float* __restrict__ eb1, const float* __restrict__ eb2,
    const float* __restrict__ qb, const float* __restrict__ kb,
    const float* __restrict__ vb, const float* __restrict__ nb1,
    const float* __restrict__ nb2, const float* __restrict__ g1,
    const float* __restrict__ be1, const float* __restrict__ g2,
    const float* __restrict__ be2, const float* __restrict__ xb1,
    const float* __restrict__ xb2, const float* __restrict__ cb1,
    const float* __restrict__ cb2, const float* __restrict__ cw3,
    const float* __restrict__ cb3,
    float* __restrict__ accg, float* __restrict__ hng, float* __restrict__ efg) {
    // LDS: 24960 shorts = 49,920 B -> 3 blocks/CU. Overlays by lifetime:
    //  hb  [20][96] : h (P0-P8) -> hn (P10-P11)
    //  S1  [80][96] : t1(P1-2) | sc f32 rows0-4(P5-7) | qag rows48-67(P3-8)
    //                 t1b rows0-31(P8-9) | outb f32 rows32-71(P9-10) | xs(P11-14)
    //  efb [80][96] : ef(P2-12) -> A0(P12-13) -> cw3e/bcb/trs f32 (P14-17)
    //  kvb [80][96] : ea(P0-1) -> kh(P4-5) -> vh(P6-7) -> ea again(P8-11) -> A2(P14-15)
    __shared__ __align__(16) short smem[24960];
    short* hb  = smem;            // 1920
    short* S1  = smem + 1920;     // 7680
    short* efb = smem + 9600;     // 7680
    short* kvb = smem + 17280;    // 7680
    short* qag = S1 + 48 * 96;    // rows 48-67 of S1
    float* sc   = (float*)S1;             // 240 f32 (S1 rows 0-4)
    float* outb = (float*)(S1 + 3072);    // 1920 f32 (S1 rows 32-71), oaddr swz
    float* cw3e = (float*)efb;            // 288 f32
    float* bcb  = (float*)(efb + 576);    // 240 f32
    float* trs  = (float*)(efb + 1056);   // 320 f32

    const int t = threadIdx.x;
    const int blk = blockIdx.x;
    const int n0 = blk * NPB, e0 = blk * EPB;

    // ---- P0: stage h -> hb, ea -> kvb (bf16, swizzled) ----
    for (int i = t; i < 1920; i += 384) {
        int r = i / 24, c = (i - r * 24) * 4;
        f4 v = *(const f4*)&ea[(size_t)(e0 + r) * 96 + c];
        stpk(kvb, r, c, v);
    }
    for (int i = t; i < 480; i += 384) {
        int r = i / 24, c = (i - r * 24) * 4;
        f4 v = *(const f4*)&h[(size_t)(n0 + r) * 96 + c];
        stpk(hb, r, c, v);
    }
    __syncthreads();

    const int lane = t & 63, w = t >> 6;
    const int kg = lane >> 4, ln = lane & 15;
    const int wc0 = w * 16, col0 = wc0 + kg * 4;

    int erow[5], esrc[5], edst[5];
#pragma unroll
    for (int s = 0; s < 5; s++) {
        erow[s] = s * 16 + ln;
        int sl = erow[s] >> 2;
        esrc[s] = sl;
        int si = sl % 5, jj = erow[s] & 3;
        edst[s] = (sl / 5) * 5 + jj + (jj >= si);
    }

    f4 acc[5];
    // ---- P1: edge MLP L1 (K=288: [h[src], h[dst], ea(kvb)]) -> S1 ----
    gemmCol<288, 5>(wsT + OFF_EW1, wc0, ln, kg,
        [&](int s, int k0) -> bf8 {
            int k = k0 + kg * 8;
            if (k0 < 96)  return ldfrag(hb, esrc[s], k);
            if (k0 < 192) return ldfrag(hb, edst[s], k - 96);
            return ldfrag(kvb, erow[s], k - 192);
        }, acc);
    {
        f4 b = *(const f4*)&eb1[col0];
#pragma unroll
        for (int s = 0; s < 5; s++) {
            f4 v;
#pragma unroll
            for (int j = 0; j < 4; j++) v[j] = sp_f(acc[s][j] + b[j]);
            stpk(S1, erow[s], col0, v);
        }
    }
    __syncthreads();
    // ---- P2: edge MLP L2 (K=96) -> efb (ef) ----
    gemmCol<96, 5>(wsT + OFF_EW2, wc0, ln, kg,
        [&](int s, int k0) { return ldfrag(S1, erow[s], k0 + kg * 8); }, acc);
    {
        f4 b = *(const f4*)&eb2[col0];
#pragma unroll
        for (int s = 0; s < 5; s++) {
            f4 v;
#pragma unroll
            for (int j = 0; j < 4; j++) v[j] = sp_f(acc[s][j] + b[j]);
            stpk(efb, erow[s], col0, v);
        }
    }
    __syncthreads();
    // ---- P3: q proj -> qag ; P4: kh (K=192) -> kvb ----
    {
        f4 qa[2];
        gemmCol<96, 2>(wsT + OFF_QW, wc0, ln, kg,
            [&](int s, int k0) { return ldfrag(hb, s * 16 + ln, k0 + kg * 8); }, qa);
        f4 b = *(const f4*)&qb[col0];
#pragma unroll
        for (int s = 0; s < 2; s++) {
            int row = s * 16 + ln;
            if (row < NPB) {
                f4 v;
#pragma unroll
                for (int j = 0; j < 4; j++) v[j] = qa[s][j] + b[j];
                stpk(qag, row, col0, v);
            }
        }
    }
    gemmCol<192, 5>(wsT + OFF_KW, wc0, ln, kg,
        [&](int s, int k0) {
            int k = k0 + kg * 8;
            if (k0 < 96) return ldfrag(hb, esrc[s], k);
            return ldfrag(efb, erow[s], k - 96);
        }, acc);
    {
        f4 b = *(const f4*)&kb[col0];
#pragma unroll
        for (int s = 0; s < 5; s++) {
            f4 v;
#pragma unroll
            for (int j = 0; j < 4; j++) v[j] = acc[s][j] + b[j];
            stpk(kvb, erow[s], col0, v);   // ea in kvb dead after P1
        }
    }
    __syncthreads();
    // ---- P5a: scores (per edge x head) -> sc ----
    if (t < 240) {
        int e = t / 3, hd = t - e * 3, nd = e >> 2;
        float s = 0.f;
#pragma unroll
        for (int c8 = 0; c8 < 4; c8++) {
            int c = hd * 32 + c8 * 8;
            bf8 qv = ldfrag(qag, nd, c);
            bf8 kv = ldfrag(kvb, e, c);
#pragma unroll
            for (int j = 0; j < 8; j++) s = fmaf(frombf(qv[j]), frombf(kv[j]), s);
        }
        sc[e * 3 + hd] = s * 0.17677669529663687f;  // 1/sqrt(32)
    }
    __syncthreads();
    // ---- P5b: softmax over 4 edges ; P6: vh (K=96) -> kvb ----
    if (t < 60) {
        int nd = t / 3, hd = t - nd * 3;
        float v0 = sc[(nd * 4 + 0) * 3 + hd], v1 = sc[(nd * 4 + 1) * 3 + hd];
        float v2 = sc[(nd * 4 + 2) * 3 + hd], v3 = sc[(nd * 4 + 3) * 3 + hd];
        float m = fmaxf(fmaxf(v0, v1), fmaxf(v2, v3));
        float p0 = __expf(v0 - m), p1 = __expf(v1 - m);
        float p2 = __expf(v2 - m), p3 = __expf(v3 - m);
        float inv = 1.f / (p0 + p1 + p2 + p3);
        sc[(nd * 4 + 0) * 3 + hd] = p0 * inv;
        sc[(nd * 4 + 1) * 3 + hd] = p1 * inv;
        sc[(nd * 4 + 2) * 3 + hd] = p2 * inv;
        sc[(nd * 4 + 3) * 3 + hd] = p3 * inv;
    }
    gemmCol<96, 5>(wsT + OFF_VW, wc0, ln, kg,
        [&](int s, int k0) { return ldfrag(efb, erow[s], k0 + kg * 8); }, acc);
    {
        f4 b = *(const f4*)&vb[col0];
#pragma unroll
        for (int s = 0; s < 5; s++) {
            f4 v;
#pragma unroll
            for (int j = 0; j < 4; j++) v[j] = acc[s][j] + b[j];
            stpk(kvb, erow[s], col0, v);   // kh readers done at last barrier
        }
    }
    __syncthreads();
    // ---- P7: agg = sum attw*vh ; LayerNorm1 -> qag (vectorized) ----
    if (t < 320) {
        int nd = t >> 4, cg = t & 15;
        bool act = cg < 12;
        int hd = cg >> 2;
        float agg[8];
#pragma unroll
        for (int j = 0; j < 8; j++) agg[j] = 0.f;
        if (act) {
#pragma unroll
            for (int k = 0; k < 4; k++) {
                int e = nd * 4 + k;
                float wgt = sc[e * 3 + hd];
                bf8 v8 = ldfrag(kvb, e, cg * 8);
#pragma unroll
                for (int j = 0; j < 8; j++) agg[j] = fmaf(wgt, frombf(v8[j]), agg[j]);
            }
        }
        float s1 = 0.f, s2 = 0.f;
#pragma unroll
        for (int j = 0; j < 8; j++) { s1 += agg[j]; s2 += agg[j] * agg[j]; }
        if (!act) { s1 = 0.f; s2 = 0.f; }
        for (int m = 1; m < 16; m <<= 1) {
            s1 += __shfl_xor(s1, m);
            s2 += __shfl_xor(s2, m);
        }
        float mu = s1 * (1.f / 96.f);
        float var = s2 * (1.f / 96.f) - mu * mu;
        float rs = rsqrtf(var + 1e-5f);
        if (act) {
            int c = cg * 8;
            f4 ga = *(const f4*)&g1[c], gb = *(const f4*)&g1[c + 4];
            f4 ba = *(const f4*)&be1[c], bb = *(const f4*)&be1[c + 4];
            float o[8];
#pragma unroll
            for (int j = 0; j < 4; j++) {
                o[j] = (agg[j] - mu) * rs * ga[j] + ba[j];
                o[j + 4] = (agg[j + 4] - mu) * rs * gb[j] + bb[j];
            }
            stpk8(qag, nd, c, o);
        }
    }
    __syncthreads();
    // ---- P8: restage ea -> kvb (vh dead); node MLP L1 -> S1 rows 0-31 ----
    for (int i = t; i < 1920; i += 384) {
        int r = i / 24, c = (i - r * 24) * 4;
        f4 v = *(const f4*)&ea[(size_t)(e0 + r) * 96 + c];
        stpk(kvb, r, c, v);
    }
    {
        f4 na[2];
        gemmCol<192, 2>(wsT + OFF_NW1, wc0, ln, kg,
            [&](int s, int k0) {
                int row = s * 16 + ln, k = k0 + kg * 8;
                if (k0 < 96) return ldfrag(hb, row, k);
                return ldfrag(qag, row, k - 96);   // rows>=20 garbage, discarded
            }, na);
        f4 b = *(const f4*)&nb1[col0];
#pragma unroll
        for (int s = 0; s < 2; s++) {
            int row = s * 16 + ln;
            f4 v;
#pragma unroll
            for (int j = 0; j < 4; j++) v[j] = sp_f(na[s][j] + b[j]);
            stpk(S1, row, col0, v);   // garbage rows 20-31 harmless
        }
    }
    __syncthreads();
    // ---- P9: node MLP L2 (K=96) + residual h -> outb (S1 rows 32-71) ----
    {
        f4 na[2];
        gemmCol<96, 2>(wsT + OFF_NW2, wc0, ln, kg,
            [&](int s, int k0) { return ldfrag(S1, s * 16 + ln, k0 + kg * 8); }, na);
        f4 b = *(const f4*)&nb2[col0];
#pragma unroll
        for (int s = 0; s < 2; s++) {
            int row = s * 16 + ln;
            if (row < NPB) {
                f4 hv = *(const f4*)&h[(size_t)(n0 + row) * 96 + col0];
                f4 v;
#pragma unroll
                for (int j = 0; j < 4; j++) v[j] = na[s][j] + b[j] + hv[j];
                *(f4*)oaddr(outb, row, col0) = v;
            }
        }
    }
    __syncthreads();
    // ---- P10: LayerNorm2 -> hng global + hb (vectorized) ----
    if (t < 320) {
        int nd = t >> 4, cg = t & 15;
        bool act = cg < 12;
        float xv[8];
#pragma unroll
        for (int j = 0; j < 8; j++) xv[j] = 0.f;
        if (act) {
            f4 x0 = *(const f4*)oaddr(outb, nd, cg * 8);
            f4 x1 = *(const f4*)oaddr(outb, nd, cg * 8 + 4);
#pragma unroll
            for (int j = 0; j < 4; j++) { xv[j] = x0[j]; xv[j + 4] = x1[j]; }
        }
        float s1 = 0.f, s2 = 0.f;
#pragma unroll
        for (int j = 0; j < 8; j++) { s1 += xv[j]; s2 += xv[j] * xv[j]; }
        for (int m = 1; m < 16; m <<= 1) {
            s1 += __shfl_xor(s1, m);
            s2 += __shfl_xor(s2, m);
        }
        float mu = s1 * (1.f / 96.f);
        float var = s2 * (1.f / 96.f) - mu * mu;
        float rs = rsqrtf(var + 1e-5f);
        if (act) {
            int c = cg * 8;
            f4 ga = *(const f4*)&g2[c], gb = *(const f4*)&g2[c + 4];
            f4 ba = *(const f4*)&be2[c], bb = *(const f4*)&be2[c + 4];
            float o[8];
#pragma unroll
            for (int j = 0; j < 4; j++) {
                o[j] = (xv[j] - mu) * rs * ga[j] + ba[j];
                o[j + 4] = (xv[j + 4] - mu) * rs * gb[j] + bb[j];
            }
            f4 o0 = {o[0], o[1], o[2], o[3]}, o1 = {o[4], o[5], o[6], o[7]};
            *(f4*)&hng[(size_t)(n0 + nd) * 96 + c] = o0;
            *(f4*)&hng[(size_t)(n0 + nd) * 96 + c + 4] = o1;
            stpk8(hb, nd, c, o);
        }
    }
    __syncthreads();
    // ---- P11: enhance L1 (K=288: [hn[src], hn[dst], ea(kvb)]) -> S1 ----
    gemmCol<288, 5>(wsT + OFF_XW1, wc0, ln, kg,
        [&](int s, int k0) -> bf8 {
            int k = k0 + kg * 8;
            if (k0 < 96)  return ldfrag(hb, esrc[s], k);
            if (k0 < 192) return ldfrag(hb, edst[s], k - 96);
            return ldfrag(kvb, erow[s], k - 192);
        }, acc);
    {
        f4 b = *(const f4*)&xb1[col0];
#pragma unroll
        for (int s = 0; s < 5; s++) {
            f4 v;
#pragma unroll
            for (int j = 0; j < 4; j++) v[j] = sp_f(acc[s][j] + b[j]);
            stpk(S1, erow[s], col0, v);
        }
    }
    __syncthreads();
    // ---- P12: enhance L2 (K=96) + ef residual -> efg global + efb ----
    gemmCol<96, 5>(wsT + OFF_XW2, wc0, ln, kg,
        [&](int s, int k0) { return ldfrag(S1, erow[s], k0 + kg * 8); }, acc);
    {
        f4 b = *(const f4*)&xb2[col0];
#pragma unroll
        for (int s = 0; s < 5; s++) {
            int row = erow[s];
            s4 ev = *(const s4*)&efb[(row * 96 + col0) ^ ((row & 7) << 3)];
            f4 v;
#pragma unroll
            for (int j = 0; j < 4; j++) v[j] = acc[s][j] + b[j] + frombf(ev[j]);
            *(f4*)&efg[(size_t)(e0 + row) * 96 + col0] = v;
            stpk(efb, row, col0, v);
        }
    }
    __syncthreads();
    // ---- P13: coord MLP L1 (K=96, reads efb A0) -> S1 ----
    gemmCol<96, 5>(wsT + OFF_CW1, wc0, ln, kg,
        [&](int s, int k0) { return ldfrag(efb, erow[s], k0 + kg * 8); }, acc);
    {
        f4 b = *(const f4*)&cb1[col0];
#pragma unroll
        for (int s = 0; s < 5; s++) {
            f4 v;
#pragma unroll
            for (int j = 0; j < 4; j++) v[j] = sp_f(acc[s][j] + b[j]);
            stpk(S1, erow[s], col0, v);
        }
    }
    __syncthreads();
    // ---- P14: cw3 table -> efb region (A0 dead); coord MLP L2 -> kvb (A2) ----
    if (t < 288) cw3e[t] = cw3[t];
    gemmCol<96, 5>(wsT + OFF_CW2, wc0, ln, kg,
        [&](int s, int k0) { return ldfrag(S1, erow[s], k0 + kg * 8); }, acc);
    {
        f4 b = *(const f4*)&cb2[col0];
#pragma unroll
        for (int s = 0; s < 5; s++) {
            f4 v;
#pragma unroll
            for (int j = 0; j < 4; j++) v[j] = sp_f(acc[s][j] + b[j]);
            stpk(kvb, erow[s], col0, v);
        }
    }
    __syncthreads();
    // ---- P15: bc = A2 @ cw3 + cb3 -> bcb ----
    if (t < 240) {
        int e = t / 3, j = t - e * 3;
        float s = cb3[j];
#pragma unroll
        for (int c8 = 0; c8 < 12; c8++) {
            bf8 av = ldfrag(kvb, e, c8 * 8);
#pragma unroll
            for (int jj = 0; jj < 8; jj++)
                s = fmaf(frombf(av[jj]), cw3e[(c8 * 8 + jj) * 3 + j], s);
        }
        bcb[e * 3 + j] = s;
    }
    __syncthreads();
    // ---- P16: geometry per edge -> trs ----
    if (t < 80) {
        int sl = t >> 2, jj = t & 3, si = sl % 5;
        int dl = (sl / 5) * 5 + jj + (jj >= si);
        int rn = n0 + sl, cn = n0 + dl;
        float r0c = cp[(size_t)rn * 3 + 0], r1c = cp[(size_t)rn * 3 + 1],
              r2c = cp[(size_t)rn * 3 + 2];
        float q0 = cp[(size_t)cn * 3 + 0], q1 = cp[(size_t)cn * 3 + 1],
              q2 = cp[(size_t)cn * 3 + 2];
        float d0 = r0c - q0, d1 = r1c - q1, d2 = r2c - q2;
        float x0 = r1c * q2 - r2c * q1;
        float x1 = r2c * q0 - r0c * q2;
        float x2 = r0c * q1 - r1c * q0;
        float v0 = d1 * x2 - d2 * x1;
        float v1 = d2 * x0 - d0 * x2;
        float v2 = d0 * x1 - d1 * x0;
        float b0 = bcb[t * 3 + 0], b1 = bcb[t * 3 + 1], b2 = bcb[t * 3 + 2];
        trs[t * 4 + 0] = fminf(fmaxf(d0 * b0 + x0 * b1 + v0 * b2, -100.f), 100.f);
        trs[t * 4 + 1] = fminf(fmaxf(d1 * b0 + x1 * b1 + v1 * b2, -100.f), 100.f);
        trs[t * 4 + 2] = fminf(fmaxf(d2 * b0 + x2 * b1 + v2 * b2, -100.f), 100.f);
    }
    __syncthreads();
    // ---- P17: acc = mean over each node's 4 edges ----
    if (t < 60) {
        int nd = t / 3, j = t - nd * 3;
        float s = (trs[(nd * 4 + 0) * 4 + j] + trs[(nd * 4 + 1) * 4 + j] +
                   trs[(nd * 4 + 2) * 4 + j] + trs[(nd * 4 + 3) * 4 + j]) * 0.25f;
        accg[(size_t)(n0 + nd) * 3 + j] = s;
    }
}

extern "C" void kernel_launch(void* const* d_in, const int* in_sizes, int n_in,
                              void* d_out, int out_size, void* d_ws, size_t ws_size,
                              hipStream_t stream) {
    const float* h   = (const float*)d_in[0];
    const float* cp  = (const float*)d_in[3];   // coord_pre
    const float* ea  = (const float*)d_in[5];   // edge_attr
    const float* ew1 = (const float*)d_in[6];
    const float* eb1 = (const float*)d_in[7];
    const float* ew2 = (const float*)d_in[8];
    const float* eb2 = (const float*)d_in[9];
    const float* xw1 = (const float*)d_in[10];
    const float* xb1 = (const float*)d_in[11];
    const float* xw2 = (const float*)d_in[12];
    const float* xb2 = (const float*)d_in[13];
    const float* nw1 = (const float*)d_in[14];
    const float* nb1 = (const float*)d_in[15];
    const float* nw2 = (const float*)d_in[16];
    const float* nb2 = (const float*)d_in[17];
    const float* cw1 = (const float*)d_in[18];
    const float* cb1 = (const float*)d_in[19];
    const float* cw2 = (const float*)d_in[20];
    const float* cb2 = (const float*)d_in[21];
    const float* cw3 = (const float*)d_in[22];
    const float* cb3 = (const float*)d_in[23];
    const float* qw  = (const float*)d_in[24];
    const float* qb  = (const float*)d_in[25];
    const float* kw  = (const float*)d_in[26];
    const float* kb  = (const float*)d_in[27];
    const float* vw  = (const float*)d_in[28];
    const float* vb  = (const float*)d_in[29];
    const float* g1  = (const float*)d_in[30];
    const float* be1 = (const float*)d_in[31];
    const float* g2  = (const float*)d_in[32];
    const float* be2 = (const float*)d_in[33];

    float* out  = (float*)d_out;
    float* accg = out;                                    // [NN,3]
    float* hng  = out + (size_t)NN * 3;                   // [NN,96]
    float* efg  = out + (size_t)NN * 3 + (size_t)NN * 96; // [NE,96] ef2
    short* wsT = (short*)d_ws;                            // 313 KB of weights

    k_prep<<<11, 256, 0, stream>>>(ew1, ew2, kw, vw, qw, nw1, nw2, xw1, xw2,
                                   cw1, cw2, wsT);
    k_fused<<<B_GRAPHS / GPB, 384, 0, stream>>>(
        h, cp, ea, wsT, eb1, eb2, qb, kb, vb, nb1, nb2, g1, be1, g2, be2,
        xb1, xb2, cb1, cb2, cw3, cb3, accg, hng, efg);
}

// Round 8
// 340.231 us; speedup vs baseline: 1.4561x; 1.0459x over previous
//
#include <hip/hip_runtime.h>
#include <hip/hip_bf16.h>

#define B_GRAPHS 16384
#define NN (B_GRAPHS * 5)          // 81920 nodes
#define NE (NN * 4)                // 327680 edges
#define GPB 4                      // graphs per block
#define EPB 80                     // edges per block
#define NPB 20                     // nodes per block
#define RS 104                     // LDS row stride (elems): 208B, 16B-aligned,
                                   // rows map to 8 disjoint 4-bank groups -> conflict-free

typedef __attribute__((ext_vector_type(8))) short bf8;   // 8 x bf16
typedef __attribute__((ext_vector_type(4))) short s4;    // 4 x bf16
typedef __attribute__((ext_vector_type(4))) float f4;
typedef __attribute__((ext_vector_type(2))) unsigned u2;
typedef __attribute__((ext_vector_type(4))) unsigned u4;

// d_ws layout (bf16 elements) — all weights transposed to [N=96][K]
#define OFF_EW1 0
#define OFF_EW2 27648
#define OFF_KW  36864
#define OFF_VW  55296
#define OFF_QW  64512
#define OFF_NW1 73728
#define OFF_NW2 92160
#define OFF_XW1 101376
#define OFF_XW2 129024
#define OFF_CW1 138240
#define OFF_CW2 147456

__device__ __forceinline__ float sp_f(float x) {
    return fmaxf(x, 0.0f) + __logf(1.0f + __expf(-fabsf(x)));
}
__device__ __forceinline__ short tobf(float x) {
    return __builtin_bit_cast(short, __float2bfloat16(x));
}
__device__ __forceinline__ float frombf(short s) {
    union { float f; unsigned u; } v;
    v.u = ((unsigned)(unsigned short)s) << 16;
    return v.f;
}
__device__ __forceinline__ unsigned pk2(float a, float b) {
    unsigned lo = (unsigned short)tobf(a);
    unsigned hi = (unsigned short)tobf(b);
    return lo | (hi << 16);
}
// linear LDS accessors (off in elems; callers keep 8-elem alignment for bf8)
__device__ __forceinline__ bf8 ldL(const short* buf, int off) {
    return *(const bf8*)&buf[off];
}
__device__ __forceinline__ void stL(short* buf, int off, f4 v) {
    u2 o = {pk2(v[0], v[1]), pk2(v[2], v[3])};
    *(u2*)&buf[off] = o;
}
__device__ __forceinline__ void stL8(short* buf, int off, const float* v) {
    u4 o = {pk2(v[0], v[1]), pk2(v[2], v[3]), pk2(v[4], v[5]), pk2(v[6], v[7])};
    *(u4*)&buf[off] = o;
}

// Wave-owns-16-cols GEMM, swapped MFMA operands, WEIGHTS PREFETCHED TO REGS.
// acc[s][j] = out[row = s*16 + (lane&15)][col = wc0 + (lane>>4)*4 + j]
template <int K, int NS, class AF>
__device__ __forceinline__ void gemmCol(const short* __restrict__ wT, int wc0,
                                        int ln, int kg, AF aload, f4* acc) {
    constexpr int NK = K / 32;
    bf8 wf[NK];
    const short* wp = wT + (size_t)(wc0 + ln) * K + kg * 8;
#pragma unroll
    for (int kk = 0; kk < NK; kk++) wf[kk] = *(const bf8*)(wp + kk * 32);
#pragma unroll
    for (int s = 0; s < NS; s++) {
        acc[s][0] = 0.f; acc[s][1] = 0.f; acc[s][2] = 0.f; acc[s][3] = 0.f;
    }
#pragma unroll
    for (int kk = 0; kk < NK; kk++) {
#pragma unroll
        for (int s = 0; s < NS; s++) {
            acc[s] = __builtin_amdgcn_mfma_f32_16x16x32_bf16(wf[kk],
                                                             aload(s, kk * 32),
                                                             acc[s], 0, 0, 0);
        }
    }
}

// ---------------- Prep: transpose+convert weights into d_ws ------------------
__global__ __launch_bounds__(256) void k_prep(
    const float* ew1, const float* ew2, const float* kw, const float* vw,
    const float* qw, const float* nw1, const float* nw2, const float* xw1,
    const float* xw2, const float* cw1, const float* cw2, short* wsT) {
    const float* srcs[11] = {ew1, ew2, kw, vw, qw, nw1, nw2, xw1, xw2, cw1, cw2};
    const int Ks[11] = {288, 96, 192, 96, 96, 192, 96, 288, 96, 96, 96};
    const int offs[11] = {OFF_EW1, OFF_EW2, OFF_KW, OFF_VW, OFF_QW, OFF_NW1,
                          OFF_NW2, OFF_XW1, OFF_XW2, OFF_CW1, OFF_CW2};
    int b = blockIdx.x;
    const float* src = srcs[b];
    int K = Ks[b], off = offs[b];
    for (int idx = threadIdx.x; idx < K * 96; idx += 256) {
        int n = idx / K, k = idx - n * K;
        wsT[off + idx] = tobf(src[(size_t)k * 96 + n]);
    }
}

// ---------------- Fused: edge MLP + attention + node + enhance + coord -------
// LDS rows (stride RS): hb[20] | SB[40] | E1[80] | E2[80] = 220 rows = 45,760 B
// Lifetimes: E2: ea -> ef -> ef2 -> A2 ; E1: t1 -> kh -> vh -> ea(restage) -> t1e -> t1c
// SB: qh/agb rows0-19 -> outb(bf16) rows0-19 ; sc|cw3s rows20-25 ; t1b rows20-39 ;
//     bcb rows26-30 ; trs rows31-37
__global__ __launch_bounds__(384, 4) void k_fused(
    const float* __restrict__ h, const float* __restrict__ cp,
    const float* __restrict__ ea, const short* __restrict__ wsT,
    const float* __restrict__ eb1, const float* __restrict__ eb2,
    const float* __restrict__ qb, const float* __restrict__ kb,
    const float* __restrict__ vb, const float* __restrict__ nb1,
    const float* __restrict__ nb2, const float* __restrict__ g1,
    const float* __restrict__ be1, const float* __restrict__ g2,
    const float* __restrict__ be2, const float* __restrict__ xb1,
    const float* __restrict__ xb2, const float* __restrict__ cb1,
    const float* __restrict__ cb2, const float* __restrict__ cw3,
    const float* __restrict__ cb3,
    float* __restrict__ accg, float* __restrict__ hng, float* __restrict__ efg) {
    __shared__ __align__(16) short smem[220 * RS];
    short* hb = smem;                  // 20 rows
    short* SB = smem + 20 * RS;        // 40 rows
    short* E1 = smem + 60 * RS;        // 80 rows
    short* E2 = smem + 140 * RS;       // 80 rows
    float* sc   = (float*)(SB + 20 * RS);  // 240 f32 (rows 20-24), P5-P7
    float* cw3s = (float*)(SB + 20 * RS);  // 288 f32 (rows 20-25), P14+
    float* bcb  = (float*)(SB + 26 * RS);  // 240 f32 (rows 26-30)
    float* trs  = (float*)(SB + 31 * RS);  // 320 f32 (rows 31-37)

    const int t = threadIdx.x;
    const int blk = blockIdx.x;
    const int n0 = blk * NPB, e0 = blk * EPB;

    // ---- P0: stage h -> hb, ea -> E2 ----
    for (int i = t; i < 1920; i += 384) {
        int r = i / 24, c = (i - r * 24) * 4;
        f4 v = *(const f4*)&ea[(size_t)(e0 + r) * 96 + c];
        stL(E2, r * RS + c, v);
    }
    for (int i = t; i < 480; i += 384) {
        int r = i / 24, c = (i - r * 24) * 4;
        f4 v = *(const f4*)&h[(size_t)(n0 + r) * 96 + c];
        stL(hb, r * RS + c, v);
    }
    __syncthreads();

    const int lane = t & 63, w = t >> 6;
    const int kg = lane >> 4, ln = lane & 15;
    const int wc0 = w * 16, col0 = wc0 + kg * 4;

    int erow[5], ebase[5], sbase[5], dbase[5];
#pragma unroll
    for (int s = 0; s < 5; s++) {
        erow[s] = s * 16 + ln;
        int sl = erow[s] >> 2;
        int si = sl % 5, jj = erow[s] & 3;
        int dl = (sl / 5) * 5 + jj + (jj >= si);
        ebase[s] = erow[s] * RS;
        sbase[s] = sl * RS;
        dbase[s] = dl * RS;
    }

    f4 acc[5];
    // ---- P1: edge MLP L1 (K=288: [h[src], h[dst], ea(E2)]) -> t1(E1) ----
    gemmCol<288, 5>(wsT + OFF_EW1, wc0, ln, kg,
        [&](int s, int k0) -> bf8 {
            int k = k0 + kg * 8;
            if (k0 < 96)  return ldL(hb, sbase[s] + k);
            if (k0 < 192) return ldL(hb, dbase[s] + k - 96);
            return ldL(E2, ebase[s] + k - 192);
        }, acc);
    {
        f4 b = *(const f4*)&eb1[col0];
#pragma unroll
        for (int s = 0; s < 5; s++) {
            f4 v;
#pragma unroll
            for (int j = 0; j < 4; j++) v[j] = sp_f(acc[s][j] + b[j]);
            stL(E1, ebase[s] + col0, v);
        }
    }
    __syncthreads();
    // ---- P23: edge MLP L2 -> ef(E2, over dead ea) ; q proj -> qh(SB) ----
    gemmCol<96, 5>(wsT + OFF_EW2, wc0, ln, kg,
        [&](int s, int k0) { return ldL(E1, ebase[s] + k0 + kg * 8); }, acc);
    {
        f4 qa[2];
        gemmCol<96, 2>(wsT + OFF_QW, wc0, ln, kg,
            [&](int s, int k0) { return ldL(hb, (s * 16 + ln) * RS + k0 + kg * 8); },
            qa);
        f4 b = *(const f4*)&eb2[col0];
#pragma unroll
        for (int s = 0; s < 5; s++) {
            f4 v;
#pragma unroll
            for (int j = 0; j < 4; j++) v[j] = sp_f(acc[s][j] + b[j]);
            stL(E2, ebase[s] + col0, v);
        }
        f4 bq = *(const f4*)&qb[col0];
#pragma unroll
        for (int s = 0; s < 2; s++) {
            int row = s * 16 + ln;
            if (row < NPB) {
                f4 v;
#pragma unroll
                for (int j = 0; j < 4; j++) v[j] = qa[s][j] + bq[j];
                stL(SB, row * RS + col0, v);
            }
        }
    }
    __syncthreads();
    // ---- P4: kh (K=192: [h[src], ef]) -> E1 (t1 dead) ----
    gemmCol<192, 5>(wsT + OFF_KW, wc0, ln, kg,
        [&](int s, int k0) {
            int k = k0 + kg * 8;
            if (k0 < 96) return ldL(hb, sbase[s] + k);
            return ldL(E2, ebase[s] + k - 96);
        }, acc);
    {
        f4 b = *(const f4*)&kb[col0];
#pragma unroll
        for (int s = 0; s < 5; s++) {
            f4 v;
#pragma unroll
            for (int j = 0; j < 4; j++) v[j] = acc[s][j] + b[j];
            stL(E1, ebase[s] + col0, v);
        }
    }
    __syncthreads();
    // ---- P5a: scores (per edge x head) -> sc ----
    if (t < 240) {
        int e = t / 3, hd = t - e * 3, nd = e >> 2;
        float s = 0.f;
#pragma unroll
        for (int c8 = 0; c8 < 4; c8++) {
            int c = hd * 32 + c8 * 8;
            bf8 qv = ldL(SB, nd * RS + c);
            bf8 kv = ldL(E1, e * RS + c);
#pragma unroll
            for (int j = 0; j < 8; j++) s = fmaf(frombf(qv[j]), frombf(kv[j]), s);
        }
        sc[e * 3 + hd] = s * 0.17677669529663687f;  // 1/sqrt(32)
    }
    __syncthreads();
    // ---- P56: softmax (t<60) ; vh GEMM (all) -> E1 (kh dead) ----
    if (t < 60) {
        int nd = t / 3, hd = t - nd * 3;
        float v0 = sc[(nd * 4 + 0) * 3 + hd], v1 = sc[(nd * 4 + 1) * 3 + hd];
        float v2 = sc[(nd * 4 + 2) * 3 + hd], v3 = sc[(nd * 4 + 3) * 3 + hd];
        float m = fmaxf(fmaxf(v0, v1), fmaxf(v2, v3));
        float p0 = __expf(v0 - m), p1 = __expf(v1 - m);
        float p2 = __expf(v2 - m), p3 = __expf(v3 - m);
        float inv = 1.f / (p0 + p1 + p2 + p3);
        sc[(nd * 4 + 0) * 3 + hd] = p0 * inv;
        sc[(nd * 4 + 1) * 3 + hd] = p1 * inv;
        sc[(nd * 4 + 2) * 3 + hd] = p2 * inv;
        sc[(nd * 4 + 3) * 3 + hd] = p3 * inv;
    }
    gemmCol<96, 5>(wsT + OFF_VW, wc0, ln, kg,
        [&](int s, int k0) { return ldL(E2, ebase[s] + k0 + kg * 8); }, acc);
    {
        f4 b = *(const f4*)&vb[col0];
#pragma unroll
        for (int s = 0; s < 5; s++) {
            f4 v;
#pragma unroll
            for (int j = 0; j < 4; j++) v[j] = acc[s][j] + b[j];
            stL(E1, ebase[s] + col0, v);
        }
    }
    __syncthreads();
    // ---- P7: agg = sum attw*vh ; LayerNorm1 -> agb(SB rows0-19, qh dead) ----
    if (t < 320) {
        int nd = t >> 4, cg = t & 15;
        bool act = cg < 12;
        int hd = cg >> 2;
        float agg[8];
#pragma unroll
        for (int j = 0; j < 8; j++) agg[j] = 0.f;
        if (act) {
#pragma unroll
            for (int k = 0; k < 4; k++) {
                int e = nd * 4 + k;
                float wgt = sc[e * 3 + hd];
                bf8 v8 = ldL(E1, e * RS + cg * 8);
#pragma unroll
                for (int j = 0; j < 8; j++) agg[j] = fmaf(wgt, frombf(v8[j]), agg[j]);
            }
        }
        float s1 = 0.f, s2 = 0.f;
#pragma unroll
        for (int j = 0; j < 8; j++) { s1 += agg[j]; s2 += agg[j] * agg[j]; }
        if (!act) { s1 = 0.f; s2 = 0.f; }
        for (int m = 1; m < 16; m <<= 1) {
            s1 += __shfl_xor(s1, m);
            s2 += __shfl_xor(s2, m);
        }
        float mu = s1 * (1.f / 96.f);
        float var = s2 * (1.f / 96.f) - mu * mu;
        float rs = rsqrtf(var + 1e-5f);
        if (act) {
            int c = cg * 8;
            f4 ga = *(const f4*)&g1[c], gb = *(const f4*)&g1[c + 4];
            f4 ba = *(const f4*)&be1[c], bb = *(const f4*)&be1[c + 4];
            float o[8];
#pragma unroll
            for (int j = 0; j < 4; j++) {
                o[j] = (agg[j] - mu) * rs * ga[j] + ba[j];
                o[j + 4] = (agg[j + 4] - mu) * rs * gb[j] + bb[j];
            }
            stL8(SB, nd * RS + c, o);
        }
    }
    __syncthreads();
    // ---- P8: ea loads issued early; node MLP L1 -> t1b(SB rows20-39);
    //          then ea regs -> E1 (vh dead) ----
    {
        f4 eav[5];
        int rr[5], cc[5];
#pragma unroll
        for (int u = 0; u < 5; u++) {
            int i = t + u * 384;
            rr[u] = i / 24; cc[u] = (i - rr[u] * 24) * 4;
            eav[u] = *(const f4*)&ea[(size_t)(e0 + rr[u]) * 96 + cc[u]];
        }
        f4 na[2];
        gemmCol<192, 2>(wsT + OFF_NW1, wc0, ln, kg,
            [&](int s, int k0) {
                int row = s * 16 + ln, k = k0 + kg * 8;
                if (k0 < 96) return ldL(hb, row * RS + k);
                return ldL(SB, row * RS + k - 96);   // rows>=20 garbage, discarded
            }, na);
        f4 b = *(const f4*)&nb1[col0];
#pragma unroll
        for (int s = 0; s < 2; s++) {
            int row = s * 16 + ln;
            if (row < NPB) {
                f4 v;
#pragma unroll
                for (int j = 0; j < 4; j++) v[j] = sp_f(na[s][j] + b[j]);
                stL(SB, (20 + row) * RS + col0, v);
            }
        }
#pragma unroll
        for (int u = 0; u < 5; u++) stL(E1, rr[u] * RS + cc[u], eav[u]);
    }
    __syncthreads();
    // ---- P9: node MLP L2 + residual h -> outb bf16 (SB rows0-19) ----
    {
        f4 na[2];
        gemmCol<96, 2>(wsT + OFF_NW2, wc0, ln, kg,
            [&](int s, int k0) {
                return ldL(SB, (20 + s * 16 + ln) * RS + k0 + kg * 8);
            }, na);
        f4 b = *(const f4*)&nb2[col0];
#pragma unroll
        for (int s = 0; s < 2; s++) {
            int row = s * 16 + ln;
            if (row < NPB) {
                f4 hv = *(const f4*)&h[(size_t)(n0 + row) * 96 + col0];
                f4 v;
#pragma unroll
                for (int j = 0; j < 4; j++) v[j] = na[s][j] + b[j] + hv[j];
                stL(SB, row * RS + col0, v);
            }
        }
    }
    __syncthreads();
    // ---- P10: LayerNorm2 -> hng global + hb(hn) ----
    if (t < 320) {
        int nd = t >> 4, cg = t & 15;
        bool act = cg < 12;
        float xv[8];
#pragma unroll
        for (int j = 0; j < 8; j++) xv[j] = 0.f;
        if (act) {
            bf8 x = ldL(SB, nd * RS + cg * 8);
#pragma unroll
            for (int j = 0; j < 8; j++) xv[j] = frombf(x[j]);
        }
        float s1 = 0.f, s2 = 0.f;
#pragma unroll
        for (int j = 0; j < 8; j++) { s1 += xv[j]; s2 += xv[j] * xv[j]; }
        for (int m = 1; m < 16; m <<= 1) {
            s1 += __shfl_xor(s1, m);
            s2 += __shfl_xor(s2, m);
        }
        float mu = s1 * (1.f / 96.f);
        float var = s2 * (1.f / 96.f) - mu * mu;
        float rs = rsqrtf(var + 1e-5f);
        if (act) {
            int c = cg * 8;
            f4 ga = *(const f4*)&g2[c], gb = *(const f4*)&g2[c + 4];
            f4 ba = *(const f4*)&be2[c], bb = *(const f4*)&be2[c + 4];
            float o[8];
#pragma unroll
            for (int j = 0; j < 4; j++) {
                o[j] = (xv[j] - mu) * rs * ga[j] + ba[j];
                o[j + 4] = (xv[j + 4] - mu) * rs * gb[j] + bb[j];
            }
            f4 o0 = {o[0], o[1], o[2], o[3]}, o1 = {o[4], o[5], o[6], o[7]};
            *(f4*)&hng[(size_t)(n0 + nd) * 96 + c] = o0;
            *(f4*)&hng[(size_t)(n0 + nd) * 96 + c + 4] = o1;
            stL8(hb, nd * RS + c, o);
        }
    }
    __syncthreads();
    // ---- P11: enhance L1 (K=288: [hn[src], hn[dst], ea(E1)]) -> t1e(E1) ----
    gemmCol<288, 5>(wsT + OFF_XW1, wc0, ln, kg,
        [&](int s, int k0) -> bf8 {
            int k = k0 + kg * 8;
            if (k0 < 96)  return ldL(hb, sbase[s] + k);
            if (k0 < 192) return ldL(hb, dbase[s] + k - 96);
            return ldL(E1, ebase[s] + k - 192);
        }, acc);
    __syncthreads();   // all ea reads done before t1e overwrites E1
    {
        f4 b = *(const f4*)&xb1[col0];
#pragma unroll
        for (int s = 0; s < 5; s++) {
            f4 v;
#pragma unroll
            for (int j = 0; j < 4; j++) v[j] = sp_f(acc[s][j] + b[j]);
            stL(E1, ebase[s] + col0, v);
        }
    }
    __syncthreads();
    // ---- P12: enhance L2 + ef residual -> efg global + ef2(E2 in place) ----
    gemmCol<96, 5>(wsT + OFF_XW2, wc0, ln, kg,
        [&](int s, int k0) { return ldL(E1, ebase[s] + k0 + kg * 8); }, acc);
    {
        f4 b = *(const f4*)&xb2[col0];
#pragma unroll
        for (int s = 0; s < 5; s++) {
            s4 ev = *(const s4*)&E2[ebase[s] + col0];
            f4 v;
#pragma unroll
            for (int j = 0; j < 4; j++) v[j] = acc[s][j] + b[j] + frombf(ev[j]);
            *(f4*)&efg[(size_t)(e0 + erow[s]) * 96 + col0] = v;
            stL(E2, ebase[s] + col0, v);
        }
    }
    __syncthreads();
    // ---- P13: coord MLP L1 (reads ef2=E2) -> t1c(E1, t1e dead) ----
    gemmCol<96, 5>(wsT + OFF_CW1, wc0, ln, kg,
        [&](int s, int k0) { return ldL(E2, ebase[s] + k0 + kg * 8); }, acc);
    {
        f4 b = *(const f4*)&cb1[col0];
#pragma unroll
        for (int s = 0; s < 5; s++) {
            f4 v;
#pragma unroll
            for (int j = 0; j < 4; j++) v[j] = sp_f(acc[s][j] + b[j]);
            stL(E1, ebase[s] + col0, v);
        }
    }
    __syncthreads();
    // ---- P14: stage cw3 ; coord MLP L2 -> A2(E2, ef2 dead) ----
    if (t < 288) cw3s[t] = cw3[t];
    gemmCol<96, 5>(wsT + OFF_CW2, wc0, ln, kg,
        [&](int s, int k0) { return ldL(E1, ebase[s] + k0 + kg * 8); }, acc);
    {
        f4 b = *(const f4*)&cb2[col0];
#pragma unroll
        for (int s = 0; s < 5; s++) {
            f4 v;
#pragma unroll
            for (int j = 0; j < 4; j++) v[j] = sp_f(acc[s][j] + b[j]);
            stL(E2, ebase[s] + col0, v);
        }
    }
    __syncthreads();
    // ---- P15: bc = A2 @ cw3 + cb3 -> bcb ----
    if (t < 240) {
        int e = t / 3, j = t - e * 3;
        float s = cb3[j];
#pragma unroll
        for (int c8 = 0; c8 < 12; c8++) {
            bf8 av = ldL(E2, e * RS + c8 * 8);
#pragma unroll
            for (int jj = 0; jj < 8; jj++)
                s = fmaf(frombf(av[jj]), cw3s[(c8 * 8 + jj) * 3 + j], s);
        }
        bcb[e * 3 + j] = s;
    }
    __syncthreads();
    // ---- P16: geometry per edge -> trs ----
    if (t < 80) {
        int sl = t >> 2, jj = t & 3, si = sl % 5;
        int dl = (sl / 5) * 5 + jj + (jj >= si);
        int rn = n0 + sl, cn = n0 + dl;
        float r0c = cp[(size_t)rn * 3 + 0], r1c = cp[(size_t)rn * 3 + 1],
              r2c = cp[(size_t)rn * 3 + 2];
        float q0 = cp[(size_t)cn * 3 + 0], q1 = cp[(size_t)cn * 3 + 1],
              q2 = cp[(size_t)cn * 3 + 2];
        float d0 = r0c - q0, d1 = r1c - q1, d2 = r2c - q2;
        float x0 = r1c * q2 - r2c * q1;
        float x1 = r2c * q0 - r0c * q2;
        float x2 = r0c * q1 - r1c * q0;
        float v0 = d1 * x2 - d2 * x1;
        float v1 = d2 * x0 - d0 * x2;
        float v2 = d0 * x1 - d1 * x0;
        float b0 = bcb[t * 3 + 0], b1 = bcb[t * 3 + 1], b2 = bcb[t * 3 + 2];
        trs[t * 4 + 0] = fminf(fmaxf(d0 * b0 + x0 * b1 + v0 * b2, -100.f), 100.f);
        trs[t * 4 + 1] = fminf(fmaxf(d1 * b0 + x1 * b1 + v1 * b2, -100.f), 100.f);
        trs[t * 4 + 2] = fminf(fmaxf(d2 * b0 + x2 * b1 + v2 * b2, -100.f), 100.f);
    }
    __syncthreads();
    // ---- P17: acc = mean over each node's 4 edges ----
    if (t < 60) {
        int nd = t / 3, j = t - nd * 3;
        float s = (trs[(nd * 4 + 0) * 4 + j] + trs[(nd * 4 + 1) * 4 + j] +
                   trs[(nd * 4 + 2) * 4 + j] + trs[(nd * 4 + 3) * 4 + j]) * 0.25f;
        accg[(size_t)(n0 + nd) * 3 + j] = s;
    }
}

extern "C" void kernel_launch(void* const* d_in, const int* in_sizes, int n_in,
                              void* d_out, int out_size, void* d_ws, size_t ws_size,
                              hipStream_t stream) {
    const float* h   = (const float*)d_in[0];
    const float* cp  = (const float*)d_in[3];   // coord_pre
    const float* ea  = (const float*)d_in[5];   // edge_attr
    const float* ew1 = (const float*)d_in[6];
    const float* eb1 = (const float*)d_in[7];
    const float* ew2 = (const float*)d_in[8];
    const float* eb2 = (const float*)d_in[9];
    const float* xw1 = (const float*)d_in[10];
    const float* xb1 = (const float*)d_in[11];
    const float* xw2 = (const float*)d_in[12];
    const float* xb2 = (const float*)d_in[13];
    const float* nw1 = (const float*)d_in[14];
    const float* nb1 = (const float*)d_in[15];
    const float* nw2 = (const float*)d_in[16];
    const float* nb2 = (const float*)d_in[17];
    const float* cw1 = (const float*)d_in[18];
    const float* cb1 = (const float*)d_in[19];
    const float* cw2 = (const float*)d_in[20];
    const float* cb2 = (const float*)d_in[21];
    const float* cw3 = (const float*)d_in[22];
    const float* cb3 = (const float*)d_in[23];
    const float* qw  = (const float*)d_in[24];
    const float* qb  = (const float*)d_in[25];
    const float* kw  = (const float*)d_in[26];
    const float* kb  = (const float*)d_in[27];
    const float* vw  = (const float*)d_in[28];
    const float* vb  = (const float*)d_in[29];
    const float* g1  = (const float*)d_in[30];
    const float* be1 = (const float*)d_in[31];
    const float* g2  = (const float*)d_in[32];
    const float* be2 = (const float*)d_in[33];

    float* out  = (float*)d_out;
    float* accg = out;                                    // [NN,3]
    float* hng  = out + (size_t)NN * 3;                   // [NN,96]
    float* efg  = out + (size_t)NN * 3 + (size_t)NN * 96; // [NE,96] ef2
    short* wsT = (short*)d_ws;                            // 313 KB of weights

    k_prep<<<11, 256, 0, stream>>>(ew1, ew2, kw, vw, qw, nw1, nw2, xw1, xw2,
                                   cw1, cw2, wsT);
    k_fused<<<B_GRAPHS / GPB, 384, 0, stream>>>(
        h, cp, ea, wsT, eb1, eb2, qb, kb, vb, nb1, nb2, g1, be1, g2, be2,
        xb1, xb2, cb1, cb2, cw3, cb3, accg, hng, efg);
}